// Round 1
// baseline (281.077 us; speedup 1.0000x reference)
//
#include <hip/hip_runtime.h>
#include <hip/hip_bf16.h>

#define D_MODEL 128
#define SEQ_L   4096
#define BATCH   128
#define TM      64   // tokens per kconv block

typedef float f4 __attribute__((ext_vector_type(4)));
typedef float f32x4 __attribute__((ext_vector_type(4)));
typedef short bf16x8 __attribute__((ext_vector_type(8)));

__device__ __forceinline__ unsigned short f2bf(float f) {
    union { float f; unsigned u; } v; v.f = f;
    unsigned r = v.u + 0x7FFFu + ((v.u >> 16) & 1u);
    return (unsigned short)(r >> 16);
}

// ---------------- kernel 1: partial mean over L ----------------
// grid (4, 128): seg, batch. 256 threads. part[b][seg][128] = sum over 1024 tokens.
__global__ __launch_bounds__(256) void kmean(const float* __restrict__ x,
                                             float* __restrict__ part) {
    int seg = blockIdx.x, b = blockIdx.y;
    int t = threadIdx.x;
    int c4 = t & 31, ph = t >> 5;
    const f4* xb = reinterpret_cast<const f4*>(x + (size_t)b * SEQ_L * D_MODEL);
    int l0 = seg * 1024;
    f4 acc = {0.f, 0.f, 0.f, 0.f};
    for (int l = l0 + ph; l < l0 + 1024; l += 8)
        acc += xb[l * 32 + c4];
    __shared__ f4 red[256];
    red[t] = acc;
    __syncthreads();
    if (t < 32) {
        f4 s = red[t];
        #pragma unroll
        for (int p = 1; p < 8; ++p) s += red[t + 32 * p];
        reinterpret_cast<f4*>(part + ((size_t)b * 4 + seg) * D_MODEL)[t] = s;
    }
}

// ---------------- kernel 2: per-channel MLP + softmax -> w[3][128] ----------------
__global__ __launch_bounds__(128) void kweights(const float* __restrict__ part,
                                                const float* __restrict__ W1,
                                                const float* __restrict__ b1,
                                                const float* __restrict__ W2,
                                                const float* __restrict__ b2,
                                                float* __restrict__ w) {
    int c = threadIdx.x; // 0..127  (channel == pooled-batch row)
    const f4* p0 = reinterpret_cast<const f4*>(part + ((size_t)c * 4 + 0) * D_MODEL);
    const f4* p1 = reinterpret_cast<const f4*>(part + ((size_t)c * 4 + 1) * D_MODEL);
    const f4* p2 = reinterpret_cast<const f4*>(part + ((size_t)c * 4 + 2) * D_MODEL);
    const f4* p3 = reinterpret_cast<const f4*>(part + ((size_t)c * 4 + 3) * D_MODEL);
    f4 mv[32];
    #pragma unroll
    for (int d4 = 0; d4 < 32; ++d4)
        mv[d4] = (p0[d4] + p1[d4] + p2[d4] + p3[d4]) * (1.0f / (float)SEQ_L);

    float h[32];
    #pragma unroll
    for (int j = 0; j < 32; ++j) {
        const f4* w1r = reinterpret_cast<const f4*>(W1 + j * 128);
        f4 s4 = {0.f, 0.f, 0.f, 0.f};
        #pragma unroll
        for (int d4 = 0; d4 < 32; ++d4) s4 += mv[d4] * w1r[d4];
        float s = s4[0] + s4[1] + s4[2] + s4[3] + b1[j];
        h[j] = 0.5f * s * (1.0f + erff(s * 0.70710678118654752f)); // exact gelu
    }
    float lg[3];
    float mx = -1e30f;
    #pragma unroll
    for (int k = 0; k < 3; ++k) {
        float s = b2[k];
        #pragma unroll
        for (int j = 0; j < 32; ++j) s += h[j] * W2[k * 32 + j];
        lg[k] = s;
        mx = fmaxf(mx, s);
    }
    float e[3], den = 0.f;
    #pragma unroll
    for (int k = 0; k < 3; ++k) { e[k] = __expf(lg[k] - mx); den += e[k]; }
    float inv = 1.0f / den;
    #pragma unroll
    for (int k = 0; k < 3; ++k) w[k * 128 + c] = e[k] * inv;
}

// ---------------- kernel 2b: Wc fp32 -> bf16 ----------------
__global__ __launch_bounds__(256) void kcvt(const float* __restrict__ Wc,
                                            unsigned short* __restrict__ wcb) {
    int i = blockIdx.x * 256 + threadIdx.x; // 4096 threads, 4 floats each
    f4 v = reinterpret_cast<const f4*>(Wc)[i];
    ushort4 o;
    o.x = f2bf(v[0]); o.y = f2bf(v[1]); o.z = f2bf(v[2]); o.w = f2bf(v[3]);
    reinterpret_cast<ushort4*>(wcb)[i] = o;
}

// ---------------- kernel 3: fused depthwise-conv + pointwise matmul ----------------
// grid (SEQ_L/TM, BATCH), 256 threads = 4 waves.
__global__ __launch_bounds__(256) void kconv(const float* __restrict__ x,
                                             const float* __restrict__ w,
                                             const unsigned short* __restrict__ wcb,
                                             const float* __restrict__ bc,
                                             float* __restrict__ out) {
    __shared__ __align__(16) unsigned short y_lds[TM][136];
    __shared__ __align__(16) unsigned short wc_lds[128][136];

    int t = threadIdx.x;
    int b = blockIdx.y;
    int l0 = blockIdx.x * TM;
    const float* xb = x + (size_t)b * SEQ_L * D_MODEL;

    // conv taps for this thread's channel quad
    int c4 = t & 31;
    f4 w0 = reinterpret_cast<const f4*>(w)[c4];
    f4 w1 = reinterpret_cast<const f4*>(w + 128)[c4];
    f4 w2 = reinterpret_cast<const f4*>(w + 256)[c4];

    // build y tile (bf16) : y[l][c] = x[l-1]*w0 + x[l]*w1 + x[l+1]*w2
    #pragma unroll
    for (int rp = 0; rp < 8; ++rp) {
        int r = (t >> 5) + rp * 8;
        int l = l0 + r;
        f4 xm = {0.f, 0.f, 0.f, 0.f}, xp = {0.f, 0.f, 0.f, 0.f};
        f4 x0 = reinterpret_cast<const f4*>(xb + (size_t)l * D_MODEL)[c4];
        if (l > 0)         xm = reinterpret_cast<const f4*>(xb + (size_t)(l - 1) * D_MODEL)[c4];
        if (l < SEQ_L - 1) xp = reinterpret_cast<const f4*>(xb + (size_t)(l + 1) * D_MODEL)[c4];
        f4 y = xm * w0 + x0 * w1 + xp * w2;
        ushort4 yb;
        yb.x = f2bf(y[0]); yb.y = f2bf(y[1]); yb.z = f2bf(y[2]); yb.w = f2bf(y[3]);
        *reinterpret_cast<ushort4*>(&y_lds[r][c4 * 4]) = yb;
    }

    // stage Wc (bf16) into LDS, row-major [co][c] with +8 pad
    {
        int row = t >> 4;      // 16 rows per pass
        int u8 = t & 15;       // 16B chunk (8 ushorts)
        #pragma unroll
        for (int p = 0; p < 8; ++p) {
            int rr = row + p * 16;
            uint4 v = reinterpret_cast<const uint4*>(wcb + (size_t)rr * 128)[u8];
            *reinterpret_cast<uint4*>(&wc_lds[rr][u8 * 8]) = v;
        }
    }
    __syncthreads();

    // MFMA: each wave does 16 rows x 128 cols
    int lane = t & 63, wid = t >> 6;
    int m0 = wid * 16;
    int arow = m0 + (lane & 15);
    int kb = (lane >> 4) * 8;

    f32x4 acc[8];
    #pragma unroll
    for (int n = 0; n < 8; ++n) acc[n] = (f32x4){0.f, 0.f, 0.f, 0.f};

    #pragma unroll
    for (int kc = 0; kc < 4; ++kc) {
        bf16x8 a = *reinterpret_cast<const bf16x8*>(&y_lds[arow][kc * 32 + kb]);
        #pragma unroll
        for (int n = 0; n < 8; ++n) {
            bf16x8 bf = *reinterpret_cast<const bf16x8*>(&wc_lds[n * 16 + (lane & 15)][kc * 32 + kb]);
            acc[n] = __builtin_amdgcn_mfma_f32_16x16x32_bf16(a, bf, acc[n], 0, 0, 0);
        }
    }

    // epilogue: add bias, store fp32
    int colb = lane & 15;
    int rbase = m0 + (lane >> 4) * 4;
    #pragma unroll
    for (int n = 0; n < 8; ++n) {
        int co = n * 16 + colb;
        float bcv = bc[co];
        #pragma unroll
        for (int rr = 0; rr < 4; ++rr) {
            int l = l0 + rbase + rr;
            out[((size_t)b * SEQ_L + l) * D_MODEL + co] = acc[n][rr] + bcv;
        }
    }
}

extern "C" void kernel_launch(void* const* d_in, const int* in_sizes, int n_in,
                              void* d_out, int out_size, void* d_ws, size_t ws_size,
                              hipStream_t stream) {
    const float* x  = (const float*)d_in[0];
    const float* W1 = (const float*)d_in[1];
    const float* b1 = (const float*)d_in[2];
    const float* W2 = (const float*)d_in[3];
    const float* b2 = (const float*)d_in[4];
    const float* Wc = (const float*)d_in[5];
    const float* bc = (const float*)d_in[6];
    float* out = (float*)d_out;

    char* ws = (char*)d_ws;
    float* part = (float*)ws;                         // 128*4*128*4 = 256 KB
    float* w    = (float*)(ws + 262144);              // 3*128*4 = 1.5 KB
    unsigned short* wcb = (unsigned short*)(ws + 264192); // 128*128*2 = 32 KB

    kmean<<<dim3(4, BATCH), 256, 0, stream>>>(x, part);
    kweights<<<1, 128, 0, stream>>>(part, W1, b1, W2, b2, w);
    kcvt<<<16, 256, 0, stream>>>(Wc, wcb);
    kconv<<<dim3(SEQ_L / TM, BATCH), 256, 0, stream>>>(x, w, wcb, bc, out);
}

// Round 2
// 264.455 us; speedup vs baseline: 1.0629x; 1.0629x over previous
//
#include <hip/hip_runtime.h>
#include <hip/hip_bf16.h>

#define D_MODEL 128
#define SEQ_L   4096
#define BATCH   128
#define TM      128   // tokens per kconv block
#define NSEG    8     // kmean segments

typedef float f4 __attribute__((ext_vector_type(4)));
typedef float f32x4 __attribute__((ext_vector_type(4)));
typedef short bf16x8 __attribute__((ext_vector_type(8)));

__device__ __forceinline__ unsigned short f2bf(float f) {
    union { float f; unsigned u; } v; v.f = f;
    unsigned r = v.u + 0x7FFFu + ((v.u >> 16) & 1u);
    return (unsigned short)(r >> 16);
}

// ---------------- kernel 1: partial mean over L ----------------
// grid (NSEG, 128): seg, batch. 256 threads. part[b][seg][128] = sum over 512 tokens.
__global__ __launch_bounds__(256) void kmean(const float* __restrict__ x,
                                             float* __restrict__ part) {
    int seg = blockIdx.x, b = blockIdx.y;
    int t = threadIdx.x;
    int c4 = t & 31, ph = t >> 5;
    const f4* xb = reinterpret_cast<const f4*>(x + (size_t)b * SEQ_L * D_MODEL);
    int l0 = seg * (SEQ_L / NSEG);
    f4 acc = {0.f, 0.f, 0.f, 0.f};
    for (int l = l0 + ph; l < l0 + SEQ_L / NSEG; l += 8)
        acc += xb[l * 32 + c4];
    __shared__ f4 red[256];
    red[t] = acc;
    __syncthreads();
    if (t < 32) {
        f4 s = red[t];
        #pragma unroll
        for (int p = 1; p < 8; ++p) s += red[t + 32 * p];
        reinterpret_cast<f4*>(part + ((size_t)b * NSEG + seg) * D_MODEL)[t] = s;
    }
}

// ---------------- kernel 2: per-channel MLP + softmax -> w[3][128] ----------------
__global__ __launch_bounds__(128) void kweights(const float* __restrict__ part,
                                                const float* __restrict__ W1,
                                                const float* __restrict__ b1,
                                                const float* __restrict__ W2,
                                                const float* __restrict__ b2,
                                                float* __restrict__ w) {
    int c = threadIdx.x; // 0..127  (channel == pooled-batch row)
    f4 mv[32];
    #pragma unroll
    for (int d4 = 0; d4 < 32; ++d4) mv[d4] = (f4){0.f, 0.f, 0.f, 0.f};
    for (int s = 0; s < NSEG; ++s) {
        const f4* ps = reinterpret_cast<const f4*>(part + ((size_t)c * NSEG + s) * D_MODEL);
        #pragma unroll
        for (int d4 = 0; d4 < 32; ++d4) mv[d4] += ps[d4];
    }
    #pragma unroll
    for (int d4 = 0; d4 < 32; ++d4) mv[d4] *= (1.0f / (float)SEQ_L);

    float h[32];
    #pragma unroll
    for (int j = 0; j < 32; ++j) {
        const f4* w1r = reinterpret_cast<const f4*>(W1 + j * 128);
        f4 s4 = {0.f, 0.f, 0.f, 0.f};
        #pragma unroll
        for (int d4 = 0; d4 < 32; ++d4) s4 += mv[d4] * w1r[d4];
        float s = s4[0] + s4[1] + s4[2] + s4[3] + b1[j];
        h[j] = 0.5f * s * (1.0f + erff(s * 0.70710678118654752f)); // exact gelu
    }
    float lg[3];
    float mx = -1e30f;
    #pragma unroll
    for (int k = 0; k < 3; ++k) {
        float s = b2[k];
        #pragma unroll
        for (int j = 0; j < 32; ++j) s += h[j] * W2[k * 32 + j];
        lg[k] = s;
        mx = fmaxf(mx, s);
    }
    float e[3], den = 0.f;
    #pragma unroll
    for (int k = 0; k < 3; ++k) { e[k] = __expf(lg[k] - mx); den += e[k]; }
    float inv = 1.0f / den;
    #pragma unroll
    for (int k = 0; k < 3; ++k) w[k * 128 + c] = e[k] * inv;
}

// ---------------- kernel 2b: Wc fp32 -> bf16 ----------------
__global__ __launch_bounds__(256) void kcvt(const float* __restrict__ Wc,
                                            unsigned short* __restrict__ wcb) {
    int i = blockIdx.x * 256 + threadIdx.x; // 4096 threads, 4 floats each
    f4 v = reinterpret_cast<const f4*>(Wc)[i];
    ushort4 o;
    o.x = f2bf(v[0]); o.y = f2bf(v[1]); o.z = f2bf(v[2]); o.w = f2bf(v[3]);
    reinterpret_cast<ushort4*>(wcb)[i] = o;
}

// ---------------- kernel 3: fused depthwise-conv + pointwise matmul ----------------
// grid (SEQ_L/TM, BATCH), 512 threads = 8 waves. 2 blocks/CU (69.6 KB LDS).
__global__ __launch_bounds__(512, 4) void kconv(const float* __restrict__ x,
                                                const float* __restrict__ w,
                                                const unsigned short* __restrict__ wcb,
                                                const float* __restrict__ bc,
                                                float* __restrict__ out) {
    __shared__ __align__(16) unsigned short y_lds[TM][136];
    __shared__ __align__(16) unsigned short wc_lds[128][136];

    int t = threadIdx.x;
    int b = blockIdx.y;
    int l0 = blockIdx.x * TM;
    const float* xb = x + (size_t)b * SEQ_L * D_MODEL;

    // conv taps for this thread's channel quad
    int c4 = t & 31;
    f4 w0 = reinterpret_cast<const f4*>(w)[c4];
    f4 w1 = reinterpret_cast<const f4*>(w + 128)[c4];
    f4 w2 = reinterpret_cast<const f4*>(w + 256)[c4];

    // build y tile (bf16): thread owns 8 CONSECUTIVE rows -> register-shift taps.
    // y[l][c] = x[l-1]*w0 + x[l]*w1 + x[l+1]*w2
    {
        int rg = t >> 5;            // 0..15
        int r0 = rg * 8;            // first row of this thread's 8
        int lb = l0 + r0;
        f4 prev = (lb > 0) ? reinterpret_cast<const f4*>(xb + (size_t)(lb - 1) * D_MODEL)[c4]
                           : (f4){0.f, 0.f, 0.f, 0.f};
        f4 cur = reinterpret_cast<const f4*>(xb + (size_t)lb * D_MODEL)[c4];
        #pragma unroll
        for (int i = 0; i < 8; ++i) {
            int l = lb + i;
            f4 nxt = (l < SEQ_L - 1)
                         ? reinterpret_cast<const f4*>(xb + (size_t)(l + 1) * D_MODEL)[c4]
                         : (f4){0.f, 0.f, 0.f, 0.f};
            f4 y = prev * w0 + cur * w1 + nxt * w2;
            ushort4 yb;
            yb.x = f2bf(y[0]); yb.y = f2bf(y[1]); yb.z = f2bf(y[2]); yb.w = f2bf(y[3]);
            *reinterpret_cast<ushort4*>(&y_lds[r0 + i][c4 * 4]) = yb;
            prev = cur;
            cur = nxt;
        }
    }

    // stage Wc (bf16) into LDS, row-major [co][c] with +8 pad
    {
        int row = t >> 4;      // 32 rows per pass
        int u16 = t & 15;      // 16B chunk (8 ushorts)
        #pragma unroll
        for (int p = 0; p < 4; ++p) {
            int rr = row + p * 32;
            uint4 v = reinterpret_cast<const uint4*>(wcb + (size_t)rr * 128)[u16];
            *reinterpret_cast<uint4*>(&wc_lds[rr][u16 * 8]) = v;
        }
    }
    __syncthreads();

    // MFMA: each wave does 16 tokens x 128 output channels.
    // Operands SWAPPED vs naive: A = Wc rows (co), B = y rows (l)
    // => acc reg index walks co (contiguous) -> float4 stores.
    int lane = t & 63, wid = t >> 6;
    int lrow = wid * 16 + (lane & 15);   // this lane's token row (B side col idx)
    int kb = (lane >> 4) * 8;

    f32x4 acc[8];
    #pragma unroll
    for (int n = 0; n < 8; ++n) acc[n] = (f32x4){0.f, 0.f, 0.f, 0.f};

    #pragma unroll
    for (int kc = 0; kc < 4; ++kc) {
        bf16x8 by = *reinterpret_cast<const bf16x8*>(&y_lds[lrow][kc * 32 + kb]);
        #pragma unroll
        for (int n = 0; n < 8; ++n) {
            bf16x8 awc = *reinterpret_cast<const bf16x8*>(&wc_lds[n * 16 + (lane & 15)][kc * 32 + kb]);
            acc[n] = __builtin_amdgcn_mfma_f32_16x16x32_bf16(awc, by, acc[n], 0, 0, 0);
        }
    }

    // epilogue: add bias, float4 stores. lane holds l = l0+wid*16+(lane&15),
    // co = n*16 + (lane>>4)*4 + reg (contiguous over reg).
    int l = l0 + wid * 16 + (lane & 15);
    int cb = (lane >> 4) * 4;
    float* orow = out + ((size_t)b * SEQ_L + l) * D_MODEL;
    #pragma unroll
    for (int n = 0; n < 8; ++n) {
        f4 bcv = *reinterpret_cast<const f4*>(bc + n * 16 + cb);
        f4 v = acc[n] + bcv;
        *reinterpret_cast<f4*>(orow + n * 16 + cb) = v;
    }
}

extern "C" void kernel_launch(void* const* d_in, const int* in_sizes, int n_in,
                              void* d_out, int out_size, void* d_ws, size_t ws_size,
                              hipStream_t stream) {
    const float* x  = (const float*)d_in[0];
    const float* W1 = (const float*)d_in[1];
    const float* b1 = (const float*)d_in[2];
    const float* W2 = (const float*)d_in[3];
    const float* b2 = (const float*)d_in[4];
    const float* Wc = (const float*)d_in[5];
    const float* bc = (const float*)d_in[6];
    float* out = (float*)d_out;

    char* ws = (char*)d_ws;
    float* part = (float*)ws;                               // 128*8*128*4 = 512 KB
    float* w    = (float*)(ws + 524288);                    // 3*128*4 = 1.5 KB
    unsigned short* wcb = (unsigned short*)(ws + 526336);   // 128*128*2 = 32 KB

    kmean<<<dim3(NSEG, BATCH), 256, 0, stream>>>(x, part);
    kweights<<<1, 128, 0, stream>>>(part, W1, b1, W2, b2, w);
    kcvt<<<16, 256, 0, stream>>>(Wc, wcb);
    kconv<<<dim3(SEQ_L / TM, BATCH), 512, 0, stream>>>(x, w, wcb, bc, out);
}

// Round 3
// 251.910 us; speedup vs baseline: 1.1158x; 1.0498x over previous
//
#include <hip/hip_runtime.h>
#include <hip/hip_bf16.h>

#define D_MODEL 128
#define SEQ_L   4096
#define BATCH   128
#define TM      128   // tokens per kconv block
#define NSEG    8     // kmean segments
#define YPAD    132   // y_lds row stride (ushorts): 264B = 66 dwords -> 2-bank row shift

typedef float f4 __attribute__((ext_vector_type(4)));
typedef float f32x4 __attribute__((ext_vector_type(4)));
typedef short bf16x8 __attribute__((ext_vector_type(8)));

__device__ __forceinline__ unsigned short f2bf(float f) {
    union { float f; unsigned u; } v; v.f = f;
    unsigned r = v.u + 0x7FFFu + ((v.u >> 16) & 1u);
    return (unsigned short)(r >> 16);
}

// ---------------- kernel 1: partial mean over L ----------------
// grid (NSEG, 128), 512 threads. part[b][seg][128] = sum over 512 tokens.
// 1024 blocks x 8 waves = 32 waves/CU. 4 independent accumulators.
__global__ __launch_bounds__(512) void kmean(const float* __restrict__ x,
                                             float* __restrict__ part) {
    int seg = blockIdx.x, b = blockIdx.y;
    int t = threadIdx.x;
    int c4 = t & 31, ph = t >> 5;                 // ph: 0..15
    const f4* xb = reinterpret_cast<const f4*>(x + (size_t)b * SEQ_L * D_MODEL);
    int l0 = seg * (SEQ_L / NSEG);

    f4 a0 = {0.f,0.f,0.f,0.f}, a1 = a0, a2 = a0, a3 = a0;
    #pragma unroll
    for (int i = 0; i < 32; i += 4) {
        a0 += xb[(l0 + ph + (i + 0) * 16) * 32 + c4];
        a1 += xb[(l0 + ph + (i + 1) * 16) * 32 + c4];
        a2 += xb[(l0 + ph + (i + 2) * 16) * 32 + c4];
        a3 += xb[(l0 + ph + (i + 3) * 16) * 32 + c4];
    }
    f4 acc = (a0 + a1) + (a2 + a3);

    __shared__ f4 red[512];
    red[t] = acc;
    __syncthreads();
    if (t < 32) {
        f4 s = red[t];
        #pragma unroll
        for (int p = 1; p < 16; ++p) s += red[t + 32 * p];
        reinterpret_cast<f4*>(part + ((size_t)b * NSEG + seg) * D_MODEL)[t] = s;
    }
}

// ---------------- kernel 2: per-channel MLP + softmax -> w[3][128] ----------------
__global__ __launch_bounds__(128) void kweights(const float* __restrict__ part,
                                                const float* __restrict__ W1,
                                                const float* __restrict__ b1,
                                                const float* __restrict__ W2,
                                                const float* __restrict__ b2,
                                                float* __restrict__ w) {
    int c = threadIdx.x; // 0..127
    f4 mv[32];
    #pragma unroll
    for (int d4 = 0; d4 < 32; ++d4) mv[d4] = (f4){0.f, 0.f, 0.f, 0.f};
    for (int s = 0; s < NSEG; ++s) {
        const f4* ps = reinterpret_cast<const f4*>(part + ((size_t)c * NSEG + s) * D_MODEL);
        #pragma unroll
        for (int d4 = 0; d4 < 32; ++d4) mv[d4] += ps[d4];
    }
    #pragma unroll
    for (int d4 = 0; d4 < 32; ++d4) mv[d4] *= (1.0f / (float)SEQ_L);

    float h[32];
    #pragma unroll
    for (int j = 0; j < 32; ++j) {
        const f4* w1r = reinterpret_cast<const f4*>(W1 + j * 128);
        f4 s4 = {0.f, 0.f, 0.f, 0.f};
        #pragma unroll
        for (int d4 = 0; d4 < 32; ++d4) s4 += mv[d4] * w1r[d4];
        float s = s4[0] + s4[1] + s4[2] + s4[3] + b1[j];
        h[j] = 0.5f * s * (1.0f + erff(s * 0.70710678118654752f)); // exact gelu
    }
    float lg[3];
    float mx = -1e30f;
    #pragma unroll
    for (int k = 0; k < 3; ++k) {
        float s = b2[k];
        #pragma unroll
        for (int j = 0; j < 32; ++j) s += h[j] * W2[k * 32 + j];
        lg[k] = s;
        mx = fmaxf(mx, s);
    }
    float e[3], den = 0.f;
    #pragma unroll
    for (int k = 0; k < 3; ++k) { e[k] = __expf(lg[k] - mx); den += e[k]; }
    float inv = 1.0f / den;
    #pragma unroll
    for (int k = 0; k < 3; ++k) w[k * 128 + c] = e[k] * inv;
}

// ---------------- kernel 2b: Wc fp32 -> bf16 ----------------
__global__ __launch_bounds__(256) void kcvt(const float* __restrict__ Wc,
                                            unsigned short* __restrict__ wcb) {
    int i = blockIdx.x * 256 + threadIdx.x; // 4096 threads, 4 floats each
    f4 v = reinterpret_cast<const f4*>(Wc)[i];
    ushort4 o;
    o.x = f2bf(v[0]); o.y = f2bf(v[1]); o.z = f2bf(v[2]); o.w = f2bf(v[3]);
    reinterpret_cast<ushort4*>(wcb)[i] = o;
}

// ---------------- kernel 3: fused depthwise-conv + pointwise matmul ----------------
// grid (SEQ_L/TM, BATCH), 512 threads = 8 waves.
// Wc held in per-wave REGISTER A-fragments (each wave owns a 16-co block);
// LDS holds only the bf16 y tile (33.8 KB) -> low LDS-pipe load, 2 blocks/CU.
__global__ __launch_bounds__(512, 4) void kconv(const float* __restrict__ x,
                                                const float* __restrict__ w,
                                                const unsigned short* __restrict__ wcb,
                                                const float* __restrict__ bc,
                                                float* __restrict__ out) {
    __shared__ __align__(16) unsigned short y_lds[TM][YPAD];

    int t = threadIdx.x;
    int b = blockIdx.y;
    int l0 = blockIdx.x * TM;
    const float* xb = x + (size_t)b * SEQ_L * D_MODEL;

    int lane = t & 63, wid = t >> 6;
    int co0 = wid * 16;                 // this wave's output-channel block
    int arow = co0 + (lane & 15);       // A-fragment row (co)
    int kb = (lane >> 4) * 8;           // k sub-block within 32-chunk

    // preload Wc A-fragments (registers, from L2-resident wcb)
    bf16x8 awc[4];
    #pragma unroll
    for (int kc = 0; kc < 4; ++kc)
        awc[kc] = *reinterpret_cast<const bf16x8*>(wcb + (size_t)arow * 128 + kc * 32 + kb);

    // conv taps for this thread's channel quad
    int c4 = t & 31;
    f4 w0 = reinterpret_cast<const f4*>(w)[c4];
    f4 w1 = reinterpret_cast<const f4*>(w + 128)[c4];
    f4 w2 = reinterpret_cast<const f4*>(w + 256)[c4];

    // build y tile (bf16): thread owns 8 CONSECUTIVE rows -> register-shift taps.
    {
        int rg = t >> 5;            // 0..15
        int r0 = rg * 8;
        int lb = l0 + r0;
        f4 prev = (lb > 0) ? reinterpret_cast<const f4*>(xb + (size_t)(lb - 1) * D_MODEL)[c4]
                           : (f4){0.f, 0.f, 0.f, 0.f};
        f4 cur = reinterpret_cast<const f4*>(xb + (size_t)lb * D_MODEL)[c4];
        #pragma unroll
        for (int i = 0; i < 8; ++i) {
            int l = lb + i;
            f4 nxt = (l < SEQ_L - 1)
                         ? reinterpret_cast<const f4*>(xb + (size_t)(l + 1) * D_MODEL)[c4]
                         : (f4){0.f, 0.f, 0.f, 0.f};
            f4 y = prev * w0 + cur * w1 + nxt * w2;
            ushort4 yb;
            yb.x = f2bf(y[0]); yb.y = f2bf(y[1]); yb.z = f2bf(y[2]); yb.w = f2bf(y[3]);
            *reinterpret_cast<ushort4*>(&y_lds[r0 + i][c4 * 4]) = yb;
            prev = cur;
            cur = nxt;
        }
    }
    __syncthreads();

    // MFMA: wave w computes out[l0..l0+128) x co-block [co0, co0+16).
    // A = Wc rows (registers), B = y rows from LDS.
    f32x4 acc[8];
    #pragma unroll
    for (int tt = 0; tt < 8; ++tt) acc[tt] = (f32x4){0.f, 0.f, 0.f, 0.f};

    #pragma unroll
    for (int tt = 0; tt < 8; ++tt) {
        #pragma unroll
        for (int kc = 0; kc < 4; ++kc) {
            bf16x8 by = *reinterpret_cast<const bf16x8*>(&y_lds[tt * 16 + (lane & 15)][kc * 32 + kb]);
            acc[tt] = __builtin_amdgcn_mfma_f32_16x16x32_bf16(awc[kc], by, acc[tt], 0, 0, 0);
        }
    }

    // epilogue: add bias, float4 stores.
    // lane -> l = l0 + tt*16 + (lane&15), co = co0 + (lane>>4)*4 + reg
    int cb = (lane >> 4) * 4;
    f4 bcv = *reinterpret_cast<const f4*>(bc + co0 + cb);
    #pragma unroll
    for (int tt = 0; tt < 8; ++tt) {
        int l = l0 + tt * 16 + (lane & 15);
        f4 v = acc[tt] + bcv;
        *reinterpret_cast<f4*>(out + ((size_t)b * SEQ_L + l) * D_MODEL + co0 + cb) = v;
    }
}

extern "C" void kernel_launch(void* const* d_in, const int* in_sizes, int n_in,
                              void* d_out, int out_size, void* d_ws, size_t ws_size,
                              hipStream_t stream) {
    const float* x  = (const float*)d_in[0];
    const float* W1 = (const float*)d_in[1];
    const float* b1 = (const float*)d_in[2];
    const float* W2 = (const float*)d_in[3];
    const float* b2 = (const float*)d_in[4];
    const float* Wc = (const float*)d_in[5];
    const float* bc = (const float*)d_in[6];
    float* out = (float*)d_out;

    char* ws = (char*)d_ws;
    float* part = (float*)ws;                               // 128*8*128*4 = 512 KB
    float* w    = (float*)(ws + 524288);                    // 3*128*4 = 1.5 KB
    unsigned short* wcb = (unsigned short*)(ws + 526336);   // 128*128*2 = 32 KB

    kmean<<<dim3(NSEG, BATCH), 512, 0, stream>>>(x, part);
    kweights<<<1, 128, 0, stream>>>(part, W1, b1, W2, b2, w);
    kcvt<<<16, 256, 0, stream>>>(Wc, wcb);
    kconv<<<dim3(SEQ_L / TM, BATCH), 512, 0, stream>>>(x, w, wcb, bc, out);
}